// Round 1
// baseline (6203.771 us; speedup 1.0000x reference)
//
#include <hip/hip_runtime.h>
#include <hip/hip_bf16.h>

// H2GCN inference:
//   r0 = relu(x @ w_embed)                       [N,64]
//   r1 = relu([spmm(a1,r0) | spmm(a2,r0)])       [N,128]
//   r2 = relu([spmm(a1,r1) | spmm(a2,r1)])       [N,256]
//   out = softmax([r0|r1|r2] @ w_classify)       [N,16]

#define F_IN 256
#define H_DIM 64

// ---------------- embed GEMM: r0 = relu(x @ w) ----------------
// w (256x64) in LDS; each wave computes 4 rows; x row in VGPRs, broadcast
// via v_readlane so the LDS pipe serves only 1 read per k per 4 rows.
__global__ __launch_bounds__(256) void embed_gemm_relu(
    const float* __restrict__ x, const float* __restrict__ w,
    float* __restrict__ r0, int n_tiles) {
  __shared__ float ws[F_IN * H_DIM];  // 64 KB
  for (int i = threadIdx.x; i < F_IN * H_DIM / 4; i += 256)
    ((float4*)ws)[i] = ((const float4*)w)[i];
  __syncthreads();
  int lane = threadIdx.x & 63;
  int tile = blockIdx.x * 4 + (threadIdx.x >> 6);
  if (tile >= n_tiles) return;
  int row = tile * 4;
  float xv[4][4];
#pragma unroll
  for (int j = 0; j < 4; ++j)
#pragma unroll
    for (int q = 0; q < 4; ++q)
      xv[j][q] = x[(size_t)(row + j) * F_IN + q * 64 + lane];
  float acc[4] = {0.f, 0.f, 0.f, 0.f};
#pragma unroll
  for (int k = 0; k < 256; ++k) {
    float wk = ws[k * 64 + lane];
#pragma unroll
    for (int j = 0; j < 4; ++j) {
      float xb = __uint_as_float(
          __builtin_amdgcn_readlane(__float_as_uint(xv[j][k >> 6]), k & 63));
      acc[j] = fmaf(xb, wk, acc[j]);
    }
  }
#pragma unroll
  for (int j = 0; j < 4; ++j)
    r0[(size_t)(row + j) * H_DIM + lane] = fmaxf(acc[j], 0.f);
}

// ---------------- edge-parallel COO SpMM with HW float atomics ----------
// W = feature width of input (= width written). ld_out is the row stride of
// the output (concat layout). Each edge handled by W/4 threads, float4 each.
template <int W>
__global__ __launch_bounds__(256) void spmm_atomic(
    const int* __restrict__ idx, const float* __restrict__ val, int E,
    const float* __restrict__ in, float* __restrict__ out, int ld_out) {
  constexpr int TPE = W / 4;
  long long gid = (long long)blockIdx.x * 256 + threadIdx.x;
  long long e = gid / TPE;
  if (e >= E) return;
  int fq = (int)(gid % TPE) * 4;
  int row = idx[e];       // segment (output) index
  int col = idx[E + e];   // gathered (input) index
  float v = val[e];
  const float4 in4 = *(const float4*)&in[(size_t)col * W + fq];
  float* o = &out[(size_t)row * ld_out + fq];
  unsafeAtomicAdd(o + 0, v * in4.x);
  unsafeAtomicAdd(o + 1, v * in4.y);
  unsafeAtomicAdd(o + 2, v * in4.z);
  unsafeAtomicAdd(o + 3, v * in4.w);
}

__global__ __launch_bounds__(256) void relu_inplace(float4* p, long long n4) {
  long long i = (long long)blockIdx.x * 256 + threadIdx.x;
  if (i >= n4) return;
  float4 v = p[i];
  v.x = fmaxf(v.x, 0.f);
  v.y = fmaxf(v.y, 0.f);
  v.z = fmaxf(v.z, 0.f);
  v.w = fmaxf(v.w, 0.f);
  p[i] = v;
}

// ---------------- classifier + softmax --------------------------------
// One wave per node. lane = (c = lane&15, part = lane>>4); each part covers a
// quarter of each feature buffer; shuffle-reduce parts, then in-wave softmax.
__global__ __launch_bounds__(256) void classify_softmax(
    const float* __restrict__ r0, const float* __restrict__ r1,
    const float* __restrict__ r2, const float* __restrict__ wc,
    float* __restrict__ out, int n) {
  __shared__ float wls[448 * 16];  // 28 KB
  for (int i = threadIdx.x; i < 448 * 16 / 4; i += 256)
    ((float4*)wls)[i] = ((const float4*)wc)[i];
  __syncthreads();
  int lane = threadIdx.x & 63;
  int c = lane & 15;
  int part = lane >> 4;
  int node = blockIdx.x * 4 + (threadIdx.x >> 6);
  if (node >= n) return;

  float acc = 0.f;
  {  // r0: width 64, fbase 0
    const float* p = r0 + (size_t)node * 64 + part * 16;
#pragma unroll
    for (int j = 0; j < 4; ++j) {
      float4 rv = *(const float4*)(p + 4 * j);
      int fb = part * 16 + 4 * j;
      acc = fmaf(rv.x, wls[(fb + 0) * 16 + c], acc);
      acc = fmaf(rv.y, wls[(fb + 1) * 16 + c], acc);
      acc = fmaf(rv.z, wls[(fb + 2) * 16 + c], acc);
      acc = fmaf(rv.w, wls[(fb + 3) * 16 + c], acc);
    }
  }
  {  // r1: width 128, fbase 64
    const float* p = r1 + (size_t)node * 128 + part * 32;
#pragma unroll
    for (int j = 0; j < 8; ++j) {
      float4 rv = *(const float4*)(p + 4 * j);
      int fb = 64 + part * 32 + 4 * j;
      acc = fmaf(rv.x, wls[(fb + 0) * 16 + c], acc);
      acc = fmaf(rv.y, wls[(fb + 1) * 16 + c], acc);
      acc = fmaf(rv.z, wls[(fb + 2) * 16 + c], acc);
      acc = fmaf(rv.w, wls[(fb + 3) * 16 + c], acc);
    }
  }
  {  // r2: width 256, fbase 192
    const float* p = r2 + (size_t)node * 256 + part * 64;
#pragma unroll
    for (int j = 0; j < 16; ++j) {
      float4 rv = *(const float4*)(p + 4 * j);
      int fb = 192 + part * 64 + 4 * j;
      acc = fmaf(rv.x, wls[(fb + 0) * 16 + c], acc);
      acc = fmaf(rv.y, wls[(fb + 1) * 16 + c], acc);
      acc = fmaf(rv.z, wls[(fb + 2) * 16 + c], acc);
      acc = fmaf(rv.w, wls[(fb + 3) * 16 + c], acc);
    }
  }
  // reduce the 4 parts (lanes c, c+16, c+32, c+48)
  acc += __shfl_xor(acc, 16, 64);
  acc += __shfl_xor(acc, 32, 64);
  // softmax over the 16 classes (replicated in each 16-lane group)
  float m = acc;
#pragma unroll
  for (int d = 1; d < 16; d <<= 1) m = fmaxf(m, __shfl_xor(m, d, 64));
  float ex = __expf(acc - m);
  float s = ex;
#pragma unroll
  for (int d = 1; d < 16; d <<= 1) s += __shfl_xor(s, d, 64);
  if (lane < 16) out[(size_t)node * 16 + c] = ex / s;
}

extern "C" void kernel_launch(void* const* d_in, const int* in_sizes, int n_in,
                              void* d_out, int out_size, void* d_ws, size_t ws_size,
                              hipStream_t stream) {
  const float* x = (const float*)d_in[0];
  const int* a1_idx = (const int*)d_in[1];
  const float* a1_val = (const float*)d_in[2];
  const int* a2_idx = (const int*)d_in[3];
  const float* a2_val = (const float*)d_in[4];
  const float* w_embed = (const float*)d_in[5];
  const float* w_classify = (const float*)d_in[6];
  float* out = (float*)d_out;

  const int n = in_sizes[0] / F_IN;  // 50000
  const int E1 = in_sizes[2];        // 800000
  const int E2 = in_sizes[4];        // 1600000

  float* r0 = (float*)d_ws;               // n*64
  float* r1 = r0 + (size_t)n * 64;        // n*128
  float* r2 = r1 + (size_t)n * 128;       // n*256

  // zero the accumulation buffers (r1, r2)
  hipMemsetAsync(r1, 0, (size_t)n * (128 + 256) * sizeof(float), stream);

  int n_tiles = n / 4;
  embed_gemm_relu<<<(n_tiles + 3) / 4, 256, 0, stream>>>(x, w_embed, r0, n_tiles);

  auto blocks = [](long long t) { return (int)((t + 255) / 256); };

  // hop 1: width 64 -> r1 [N,128]
  spmm_atomic<64><<<blocks((long long)E1 * 16), 256, 0, stream>>>(
      a1_idx, a1_val, E1, r0, r1, 128);
  spmm_atomic<64><<<blocks((long long)E2 * 16), 256, 0, stream>>>(
      a2_idx, a2_val, E2, r0, r1 + 64, 128);
  relu_inplace<<<blocks((long long)n * 128 / 4), 256, 0, stream>>>(
      (float4*)r1, (long long)n * 128 / 4);

  // hop 2: width 128 -> r2 [N,256]
  spmm_atomic<128><<<blocks((long long)E1 * 32), 256, 0, stream>>>(
      a1_idx, a1_val, E1, r1, r2, 256);
  spmm_atomic<128><<<blocks((long long)E2 * 32), 256, 0, stream>>>(
      a2_idx, a2_val, E2, r1, r2 + 128, 256);
  relu_inplace<<<blocks((long long)n * 256 / 4), 256, 0, stream>>>(
      (float4*)r2, (long long)n * 256 / 4);

  classify_softmax<<<(n + 3) / 4, 256, 0, stream>>>(r0, r1, r2, w_classify, out, n);
}

// Round 2
// 704.334 us; speedup vs baseline: 8.8080x; 8.8080x over previous
//
#include <hip/hip_runtime.h>
#include <hip/hip_bf16.h>

// H2GCN inference:
//   r0 = relu(x @ w_embed)                       [N,64]
//   r1 = relu([spmm(a1,r0) | spmm(a2,r0)])       [N,128]
//   r2 = relu([spmm(a1,r1) | spmm(a2,r1)])       [N,256]
//   out = softmax([r0|r1|r2] @ w_classify)       [N,16]
// SpMM strategy: build CSR on-device each launch, then gather-based
// row-parallel SpMM (no float atomics, one coalesced store per row).

#define F_IN 256
#define H_DIM 64

// ---------------- embed GEMM: r0 = relu(x @ w) ----------------
__global__ __launch_bounds__(256) void embed_gemm_relu(
    const float* __restrict__ x, const float* __restrict__ w,
    float* __restrict__ r0, int n_tiles) {
  __shared__ float ws[F_IN * H_DIM];  // 64 KB
  for (int i = threadIdx.x; i < F_IN * H_DIM / 4; i += 256)
    ((float4*)ws)[i] = ((const float4*)w)[i];
  __syncthreads();
  int lane = threadIdx.x & 63;
  int tile = blockIdx.x * 4 + (threadIdx.x >> 6);
  if (tile >= n_tiles) return;
  int row = tile * 4;
  float xv[4][4];
#pragma unroll
  for (int j = 0; j < 4; ++j)
#pragma unroll
    for (int q = 0; q < 4; ++q)
      xv[j][q] = x[(size_t)(row + j) * F_IN + q * 64 + lane];
  float acc[4] = {0.f, 0.f, 0.f, 0.f};
#pragma unroll
  for (int k = 0; k < 256; ++k) {
    float wk = ws[k * 64 + lane];
#pragma unroll
    for (int j = 0; j < 4; ++j) {
      float xb = __uint_as_float(
          __builtin_amdgcn_readlane(__float_as_uint(xv[j][k >> 6]), k & 63));
      acc[j] = fmaf(xb, wk, acc[j]);
    }
  }
#pragma unroll
  for (int j = 0; j < 4; ++j)
    r0[(size_t)(row + j) * H_DIM + lane] = fmaxf(acc[j], 0.f);
}

// ---------------- CSR build -------------------------------------------
__global__ __launch_bounds__(256) void histo(const int* __restrict__ idx,
                                             int E, int* __restrict__ cnt) {
  int i = blockIdx.x * 256 + threadIdx.x;
  if (i >= E) return;
  atomicAdd(&cnt[idx[i]], 1);
}

// exclusive scan, level 1: per-block (512 elements)
__global__ __launch_bounds__(512) void scan_blocks(
    const int* __restrict__ cnt, int n, int* __restrict__ exc,
    int* __restrict__ aux) {
  __shared__ int tmp[512];
  int i = blockIdx.x * 512 + threadIdx.x;
  int v = (i < n) ? cnt[i] : 0;
  tmp[threadIdx.x] = v;
  __syncthreads();
#pragma unroll
  for (int d = 1; d < 512; d <<= 1) {
    int t = (threadIdx.x >= d) ? tmp[threadIdx.x - d] : 0;
    __syncthreads();
    tmp[threadIdx.x] += t;
    __syncthreads();
  }
  if (i < n) exc[i] = tmp[threadIdx.x] - v;   // exclusive
  if (threadIdx.x == 511) aux[blockIdx.x] = tmp[511];  // block total
}

// exclusive scan, level 2: single block over block totals (nblk <= 512)
__global__ __launch_bounds__(512) void scan_aux(int* __restrict__ aux, int nblk) {
  __shared__ int tmp[512];
  int v = (threadIdx.x < nblk) ? aux[threadIdx.x] : 0;
  tmp[threadIdx.x] = v;
  __syncthreads();
#pragma unroll
  for (int d = 1; d < 512; d <<= 1) {
    int t = (threadIdx.x >= d) ? tmp[threadIdx.x - d] : 0;
    __syncthreads();
    tmp[threadIdx.x] += t;
    __syncthreads();
  }
  if (threadIdx.x < nblk) aux[threadIdx.x] = tmp[threadIdx.x] - v;
}

__global__ __launch_bounds__(512) void add_offsets(
    int* __restrict__ rs, int* __restrict__ cur, const int* __restrict__ aux,
    int n, int E) {
  int i = blockIdx.x * 512 + threadIdx.x;
  if (i < n) {
    int v = rs[i] + aux[blockIdx.x];
    rs[i] = v;
    cur[i] = v;
  }
  if (blockIdx.x == 0 && threadIdx.x == 0) rs[n] = E;
}

__global__ __launch_bounds__(256) void scatter_edges(
    const int* __restrict__ idx, const float* __restrict__ val, int E,
    int* __restrict__ cur, int* __restrict__ ecol, float* __restrict__ eval) {
  int i = blockIdx.x * 256 + threadIdx.x;
  if (i >= E) return;
  int r = idx[i];
  int p = atomicAdd(&cur[r], 1);
  ecol[p] = idx[E + i];
  eval[p] = val[i];
}

// ---------------- gather-based CSR SpMM (+fused ReLU) ------------------
// One wave per output row. VEC=1 -> W=64 (4B/lane), VEC=2 -> W=128 (8B/lane).
template <int VEC>
__global__ __launch_bounds__(256) void spmm_csr(
    const int* __restrict__ rs, const int* __restrict__ ecol,
    const float* __restrict__ eval, const float* __restrict__ in,
    float* __restrict__ out, int ld_out, int n) {
  constexpr int W = VEC * 64;
  int lane = threadIdx.x & 63;
  int row = blockIdx.x * 4 + (threadIdx.x >> 6);
  if (row >= n) return;
  int s = rs[row], e = rs[row + 1];
  float acc0 = 0.f, acc1 = 0.f;
  int j = s;
  for (; j + 4 <= e; j += 4) {  // 4-deep MLP on gathers
    int c0 = ecol[j], c1 = ecol[j + 1], c2 = ecol[j + 2], c3 = ecol[j + 3];
    float v0 = eval[j], v1 = eval[j + 1], v2 = eval[j + 2], v3 = eval[j + 3];
    if (VEC == 1) {
      float x0 = in[(size_t)c0 * W + lane];
      float x1 = in[(size_t)c1 * W + lane];
      float x2 = in[(size_t)c2 * W + lane];
      float x3 = in[(size_t)c3 * W + lane];
      acc0 = fmaf(v0, x0, acc0);
      acc0 = fmaf(v1, x1, acc0);
      acc0 = fmaf(v2, x2, acc0);
      acc0 = fmaf(v3, x3, acc0);
    } else {
      float2 x0 = *(const float2*)&in[(size_t)c0 * W + lane * 2];
      float2 x1 = *(const float2*)&in[(size_t)c1 * W + lane * 2];
      float2 x2 = *(const float2*)&in[(size_t)c2 * W + lane * 2];
      float2 x3 = *(const float2*)&in[(size_t)c3 * W + lane * 2];
      acc0 = fmaf(v0, x0.x, acc0); acc1 = fmaf(v0, x0.y, acc1);
      acc0 = fmaf(v1, x1.x, acc0); acc1 = fmaf(v1, x1.y, acc1);
      acc0 = fmaf(v2, x2.x, acc0); acc1 = fmaf(v2, x2.y, acc1);
      acc0 = fmaf(v3, x3.x, acc0); acc1 = fmaf(v3, x3.y, acc1);
    }
  }
  for (; j < e; ++j) {
    int c = ecol[j];
    float v = eval[j];
    if (VEC == 1) {
      acc0 = fmaf(v, in[(size_t)c * W + lane], acc0);
    } else {
      float2 xv = *(const float2*)&in[(size_t)c * W + lane * 2];
      acc0 = fmaf(v, xv.x, acc0);
      acc1 = fmaf(v, xv.y, acc1);
    }
  }
  if (VEC == 1) {
    out[(size_t)row * ld_out + lane] = fmaxf(acc0, 0.f);
  } else {
    float2 st;
    st.x = fmaxf(acc0, 0.f);
    st.y = fmaxf(acc1, 0.f);
    *(float2*)&out[(size_t)row * ld_out + lane * 2] = st;
  }
}

// ---------------- classifier + softmax --------------------------------
__global__ __launch_bounds__(256) void classify_softmax(
    const float* __restrict__ r0, const float* __restrict__ r1,
    const float* __restrict__ r2, const float* __restrict__ wc,
    float* __restrict__ out, int n) {
  __shared__ float wls[448 * 16];  // 28 KB
  for (int i = threadIdx.x; i < 448 * 16 / 4; i += 256)
    ((float4*)wls)[i] = ((const float4*)wc)[i];
  __syncthreads();
  int lane = threadIdx.x & 63;
  int c = lane & 15;
  int part = lane >> 4;
  int node = blockIdx.x * 4 + (threadIdx.x >> 6);
  if (node >= n) return;

  float acc = 0.f;
  {  // r0: width 64, fbase 0
    const float* p = r0 + (size_t)node * 64 + part * 16;
#pragma unroll
    for (int j = 0; j < 4; ++j) {
      float4 rv = *(const float4*)(p + 4 * j);
      int fb = part * 16 + 4 * j;
      acc = fmaf(rv.x, wls[(fb + 0) * 16 + c], acc);
      acc = fmaf(rv.y, wls[(fb + 1) * 16 + c], acc);
      acc = fmaf(rv.z, wls[(fb + 2) * 16 + c], acc);
      acc = fmaf(rv.w, wls[(fb + 3) * 16 + c], acc);
    }
  }
  {  // r1: width 128, fbase 64
    const float* p = r1 + (size_t)node * 128 + part * 32;
#pragma unroll
    for (int j = 0; j < 8; ++j) {
      float4 rv = *(const float4*)(p + 4 * j);
      int fb = 64 + part * 32 + 4 * j;
      acc = fmaf(rv.x, wls[(fb + 0) * 16 + c], acc);
      acc = fmaf(rv.y, wls[(fb + 1) * 16 + c], acc);
      acc = fmaf(rv.z, wls[(fb + 2) * 16 + c], acc);
      acc = fmaf(rv.w, wls[(fb + 3) * 16 + c], acc);
    }
  }
  {  // r2: width 256, fbase 192
    const float* p = r2 + (size_t)node * 256 + part * 64;
#pragma unroll
    for (int j = 0; j < 16; ++j) {
      float4 rv = *(const float4*)(p + 4 * j);
      int fb = 192 + part * 64 + 4 * j;
      acc = fmaf(rv.x, wls[(fb + 0) * 16 + c], acc);
      acc = fmaf(rv.y, wls[(fb + 1) * 16 + c], acc);
      acc = fmaf(rv.z, wls[(fb + 2) * 16 + c], acc);
      acc = fmaf(rv.w, wls[(fb + 3) * 16 + c], acc);
    }
  }
  acc += __shfl_xor(acc, 16, 64);
  acc += __shfl_xor(acc, 32, 64);
  float m = acc;
#pragma unroll
  for (int d = 1; d < 16; d <<= 1) m = fmaxf(m, __shfl_xor(m, d, 64));
  float ex = __expf(acc - m);
  float s = ex;
#pragma unroll
  for (int d = 1; d < 16; d <<= 1) s += __shfl_xor(s, d, 64);
  if (lane < 16) out[(size_t)node * 16 + c] = ex / s;
}

extern "C" void kernel_launch(void* const* d_in, const int* in_sizes, int n_in,
                              void* d_out, int out_size, void* d_ws, size_t ws_size,
                              hipStream_t stream) {
  const float* x = (const float*)d_in[0];
  const int* a1_idx = (const int*)d_in[1];
  const float* a1_val = (const float*)d_in[2];
  const int* a2_idx = (const int*)d_in[3];
  const float* a2_val = (const float*)d_in[4];
  const float* w_embed = (const float*)d_in[5];
  const float* w_classify = (const float*)d_in[6];
  float* out = (float*)d_out;

  const int n = in_sizes[0] / F_IN;  // 50000
  const int E1 = in_sizes[2];        // 800000
  const int E2 = in_sizes[4];        // 1600000

  // workspace layout
  float* r0 = (float*)d_ws;                   // n*64
  float* r1 = r0 + (size_t)n * 64;            // n*128
  float* r2 = r1 + (size_t)n * 128;           // n*256
  int* cnt1 = (int*)(r2 + (size_t)n * 256);   // n
  int* cnt2 = cnt1 + n;                       // n
  int* rs1 = cnt2 + n;                        // n+1
  int* rs2 = rs1 + (n + 1);                   // n+1
  int* cur1 = rs2 + (n + 1);                  // n
  int* cur2 = cur1 + n;                       // n
  int* aux1 = cur2 + n;                       // 512
  int* aux2 = aux1 + 512;                     // 512
  int* ecol1 = aux2 + 512;                    // E1
  float* eval1 = (float*)(ecol1 + E1);        // E1
  int* ecol2 = (int*)(eval1 + E1);            // E2
  float* eval2 = (float*)(ecol2 + E2);        // E2

  auto blocks = [](long long t, int bs) { return (int)((t + bs - 1) / bs); };
  const int NB = blocks(n, 512);  // 98 <= 512

  // embed (independent of CSR build)
  embed_gemm_relu<<<blocks(n / 4, 4), 256, 0, stream>>>(x, w_embed, r0, n / 4);

  // CSR build for both graphs
  hipMemsetAsync(cnt1, 0, (size_t)2 * n * sizeof(int), stream);
  histo<<<blocks(E1, 256), 256, 0, stream>>>(a1_idx, E1, cnt1);
  histo<<<blocks(E2, 256), 256, 0, stream>>>(a2_idx, E2, cnt2);
  scan_blocks<<<NB, 512, 0, stream>>>(cnt1, n, rs1, aux1);
  scan_blocks<<<NB, 512, 0, stream>>>(cnt2, n, rs2, aux2);
  scan_aux<<<1, 512, 0, stream>>>(aux1, NB);
  scan_aux<<<1, 512, 0, stream>>>(aux2, NB);
  add_offsets<<<NB, 512, 0, stream>>>(rs1, cur1, aux1, n, E1);
  add_offsets<<<NB, 512, 0, stream>>>(rs2, cur2, aux2, n, E2);
  scatter_edges<<<blocks(E1, 256), 256, 0, stream>>>(a1_idx, a1_val, E1, cur1,
                                                     ecol1, eval1);
  scatter_edges<<<blocks(E2, 256), 256, 0, stream>>>(a2_idx, a2_val, E2, cur2,
                                                     ecol2, eval2);

  // hop 1: width 64 -> r1 [N,128]  (ReLU fused)
  spmm_csr<1><<<blocks(n, 4), 256, 0, stream>>>(rs1, ecol1, eval1, r0, r1, 128, n);
  spmm_csr<1><<<blocks(n, 4), 256, 0, stream>>>(rs2, ecol2, eval2, r0, r1 + 64, 128, n);

  // hop 2: width 128 -> r2 [N,256]  (ReLU fused)
  spmm_csr<2><<<blocks(n, 4), 256, 0, stream>>>(rs1, ecol1, eval1, r1, r2, 256, n);
  spmm_csr<2><<<blocks(n, 4), 256, 0, stream>>>(rs2, ecol2, eval2, r1, r2 + 128, 256, n);

  classify_softmax<<<blocks(n, 4), 256, 0, stream>>>(r0, r1, r2, w_classify, out, n);
}

// Round 3
// 669.095 us; speedup vs baseline: 9.2719x; 1.0527x over previous
//
#include <hip/hip_runtime.h>
#include <hip/hip_bf16.h>

// H2GCN inference:
//   r0 = relu(x @ w_embed)                       [N,64]
//   r1 = relu([spmm(a1,r0) | spmm(a2,r0)])       [N,128]
//   r2 = relu([spmm(a1,r1) | spmm(a2,r1)])       [N,256]
//   out = softmax([r0|r1|r2] @ w_classify)       [N,16]
// SpMM: on-device CSR build (histogram -> scan -> scatter of PACKED int2
// (col,val) -- one cache line per edge instead of two), then gather-based
// row-parallel SpMM with fused ReLU. No float atomics anywhere.

#define F_IN 256
#define H_DIM 64

// ---------------- embed GEMM: r0 = relu(x @ w) ----------------
__global__ __launch_bounds__(256) void embed_gemm_relu(
    const float* __restrict__ x, const float* __restrict__ w,
    float* __restrict__ r0, int n_tiles) {
  __shared__ float ws[F_IN * H_DIM];  // 64 KB
  for (int i = threadIdx.x; i < F_IN * H_DIM / 4; i += 256)
    ((float4*)ws)[i] = ((const float4*)w)[i];
  __syncthreads();
  int lane = threadIdx.x & 63;
  int tile = blockIdx.x * 4 + (threadIdx.x >> 6);
  if (tile >= n_tiles) return;
  int row = tile * 4;
  float xv[4][4];
#pragma unroll
  for (int j = 0; j < 4; ++j)
#pragma unroll
    for (int q = 0; q < 4; ++q)
      xv[j][q] = x[(size_t)(row + j) * F_IN + q * 64 + lane];
  float acc[4] = {0.f, 0.f, 0.f, 0.f};
#pragma unroll
  for (int k = 0; k < 256; ++k) {
    float wk = ws[k * 64 + lane];
#pragma unroll
    for (int j = 0; j < 4; ++j) {
      float xb = __uint_as_float(
          __builtin_amdgcn_readlane(__float_as_uint(xv[j][k >> 6]), k & 63));
      acc[j] = fmaf(xb, wk, acc[j]);
    }
  }
#pragma unroll
  for (int j = 0; j < 4; ++j)
    r0[(size_t)(row + j) * H_DIM + lane] = fmaxf(acc[j], 0.f);
}

// ---------------- CSR build -------------------------------------------
__global__ __launch_bounds__(256) void histo(const int* __restrict__ idx,
                                             int E, int* __restrict__ cnt) {
  int i = blockIdx.x * 256 + threadIdx.x;
  if (i >= E) return;
  atomicAdd(&cnt[idx[i]], 1);
}

// exclusive scan, level 1: per-block (512 elements)
__global__ __launch_bounds__(512) void scan_blocks(
    const int* __restrict__ cnt, int n, int* __restrict__ exc,
    int* __restrict__ aux) {
  __shared__ int tmp[512];
  int i = blockIdx.x * 512 + threadIdx.x;
  int v = (i < n) ? cnt[i] : 0;
  tmp[threadIdx.x] = v;
  __syncthreads();
#pragma unroll
  for (int d = 1; d < 512; d <<= 1) {
    int t = (threadIdx.x >= d) ? tmp[threadIdx.x - d] : 0;
    __syncthreads();
    tmp[threadIdx.x] += t;
    __syncthreads();
  }
  if (i < n) exc[i] = tmp[threadIdx.x] - v;            // exclusive
  if (threadIdx.x == 511) aux[blockIdx.x] = tmp[511];  // block total
}

// exclusive scan, level 2: single block over block totals (nblk <= 512)
__global__ __launch_bounds__(512) void scan_aux(int* __restrict__ aux, int nblk) {
  __shared__ int tmp[512];
  int v = (threadIdx.x < nblk) ? aux[threadIdx.x] : 0;
  tmp[threadIdx.x] = v;
  __syncthreads();
#pragma unroll
  for (int d = 1; d < 512; d <<= 1) {
    int t = (threadIdx.x >= d) ? tmp[threadIdx.x - d] : 0;
    __syncthreads();
    tmp[threadIdx.x] += t;
    __syncthreads();
  }
  if (threadIdx.x < nblk) aux[threadIdx.x] = tmp[threadIdx.x] - v;
}

__global__ __launch_bounds__(512) void add_offsets(
    int* __restrict__ rs, int* __restrict__ cur, const int* __restrict__ aux,
    int n, int E) {
  int i = blockIdx.x * 512 + threadIdx.x;
  if (i < n) {
    int v = rs[i] + aux[blockIdx.x];
    rs[i] = v;
    cur[i] = v;
  }
  if (blockIdx.x == 0 && threadIdx.x == 0) rs[n] = E;
}

// scatter packed (col, val) as one 8B write -> one cache line per edge.
__global__ __launch_bounds__(256) void scatter_edges(
    const int* __restrict__ idx, const float* __restrict__ val, int E,
    int* __restrict__ cur, int2* __restrict__ epack) {
  int i = blockIdx.x * 256 + threadIdx.x;
  if (i >= E) return;
  int r = idx[i];
  int p = atomicAdd(&cur[r], 1);
  int2 pk;
  pk.x = idx[E + i];
  pk.y = __float_as_int(val[i]);
  epack[p] = pk;
}

// ---------------- gather-based CSR SpMM (+fused ReLU) ------------------
// One wave per output row. VEC=1 -> W=64 (4B/lane), VEC=2 -> W=128 (8B/lane).
template <int VEC>
__global__ __launch_bounds__(256) void spmm_csr(
    const int* __restrict__ rs, const int2* __restrict__ epack,
    const float* __restrict__ in, float* __restrict__ out, int ld_out, int n) {
  constexpr int W = VEC * 64;
  int lane = threadIdx.x & 63;
  int row = blockIdx.x * 4 + (threadIdx.x >> 6);
  if (row >= n) return;
  int s = rs[row], e = rs[row + 1];
  float acc0 = 0.f, acc1 = 0.f;
  int j = s;
  for (; j + 8 <= e; j += 8) {  // 8-deep MLP on gathers
    int2 ep[8];
#pragma unroll
    for (int u = 0; u < 8; ++u) ep[u] = epack[j + u];
    if (VEC == 1) {
      float xg[8];
#pragma unroll
      for (int u = 0; u < 8; ++u) xg[u] = in[(size_t)ep[u].x * W + lane];
#pragma unroll
      for (int u = 0; u < 8; ++u)
        acc0 = fmaf(__int_as_float(ep[u].y), xg[u], acc0);
    } else {
      float2 xg[8];
#pragma unroll
      for (int u = 0; u < 8; ++u)
        xg[u] = *(const float2*)&in[(size_t)ep[u].x * W + lane * 2];
#pragma unroll
      for (int u = 0; u < 8; ++u) {
        float v = __int_as_float(ep[u].y);
        acc0 = fmaf(v, xg[u].x, acc0);
        acc1 = fmaf(v, xg[u].y, acc1);
      }
    }
  }
  for (; j < e; ++j) {
    int2 ep = epack[j];
    float v = __int_as_float(ep.y);
    if (VEC == 1) {
      acc0 = fmaf(v, in[(size_t)ep.x * W + lane], acc0);
    } else {
      float2 xv = *(const float2*)&in[(size_t)ep.x * W + lane * 2];
      acc0 = fmaf(v, xv.x, acc0);
      acc1 = fmaf(v, xv.y, acc1);
    }
  }
  if (VEC == 1) {
    out[(size_t)row * ld_out + lane] = fmaxf(acc0, 0.f);
  } else {
    float2 st;
    st.x = fmaxf(acc0, 0.f);
    st.y = fmaxf(acc1, 0.f);
    *(float2*)&out[(size_t)row * ld_out + lane * 2] = st;
  }
}

// ---------------- classifier + softmax --------------------------------
__global__ __launch_bounds__(256) void classify_softmax(
    const float* __restrict__ r0, const float* __restrict__ r1,
    const float* __restrict__ r2, const float* __restrict__ wc,
    float* __restrict__ out, int n) {
  __shared__ float wls[448 * 16];  // 28 KB
  for (int i = threadIdx.x; i < 448 * 16 / 4; i += 256)
    ((float4*)wls)[i] = ((const float4*)wc)[i];
  __syncthreads();
  int lane = threadIdx.x & 63;
  int c = lane & 15;
  int part = lane >> 4;
  int node = blockIdx.x * 4 + (threadIdx.x >> 6);
  if (node >= n) return;

  float acc = 0.f;
  {  // r0: width 64, fbase 0
    const float* p = r0 + (size_t)node * 64 + part * 16;
#pragma unroll
    for (int j = 0; j < 4; ++j) {
      float4 rv = *(const float4*)(p + 4 * j);
      int fb = part * 16 + 4 * j;
      acc = fmaf(rv.x, wls[(fb + 0) * 16 + c], acc);
      acc = fmaf(rv.y, wls[(fb + 1) * 16 + c], acc);
      acc = fmaf(rv.z, wls[(fb + 2) * 16 + c], acc);
      acc = fmaf(rv.w, wls[(fb + 3) * 16 + c], acc);
    }
  }
  {  // r1: width 128, fbase 64
    const float* p = r1 + (size_t)node * 128 + part * 32;
#pragma unroll
    for (int j = 0; j < 8; ++j) {
      float4 rv = *(const float4*)(p + 4 * j);
      int fb = 64 + part * 32 + 4 * j;
      acc = fmaf(rv.x, wls[(fb + 0) * 16 + c], acc);
      acc = fmaf(rv.y, wls[(fb + 1) * 16 + c], acc);
      acc = fmaf(rv.z, wls[(fb + 2) * 16 + c], acc);
      acc = fmaf(rv.w, wls[(fb + 3) * 16 + c], acc);
    }
  }
  {  // r2: width 256, fbase 192
    const float* p = r2 + (size_t)node * 256 + part * 64;
#pragma unroll
    for (int j = 0; j < 16; ++j) {
      float4 rv = *(const float4*)(p + 4 * j);
      int fb = 192 + part * 64 + 4 * j;
      acc = fmaf(rv.x, wls[(fb + 0) * 16 + c], acc);
      acc = fmaf(rv.y, wls[(fb + 1) * 16 + c], acc);
      acc = fmaf(rv.z, wls[(fb + 2) * 16 + c], acc);
      acc = fmaf(rv.w, wls[(fb + 3) * 16 + c], acc);
    }
  }
  acc += __shfl_xor(acc, 16, 64);
  acc += __shfl_xor(acc, 32, 64);
  float m = acc;
#pragma unroll
  for (int d = 1; d < 16; d <<= 1) m = fmaxf(m, __shfl_xor(m, d, 64));
  float ex = __expf(acc - m);
  float s = ex;
#pragma unroll
  for (int d = 1; d < 16; d <<= 1) s += __shfl_xor(s, d, 64);
  if (lane < 16) out[(size_t)node * 16 + c] = ex / s;
}

extern "C" void kernel_launch(void* const* d_in, const int* in_sizes, int n_in,
                              void* d_out, int out_size, void* d_ws, size_t ws_size,
                              hipStream_t stream) {
  const float* x = (const float*)d_in[0];
  const int* a1_idx = (const int*)d_in[1];
  const float* a1_val = (const float*)d_in[2];
  const int* a2_idx = (const int*)d_in[3];
  const float* a2_val = (const float*)d_in[4];
  const float* w_embed = (const float*)d_in[5];
  const float* w_classify = (const float*)d_in[6];
  float* out = (float*)d_out;

  const int n = in_sizes[0] / F_IN;  // 50000
  const int E1 = in_sizes[2];        // 800000
  const int E2 = in_sizes[4];        // 1600000

  // workspace layout
  float* r0 = (float*)d_ws;                  // n*64
  float* r1 = r0 + (size_t)n * 64;           // n*128
  float* r2 = r1 + (size_t)n * 128;          // n*256
  int* cnt1 = (int*)(r2 + (size_t)n * 256);  // n
  int* cnt2 = cnt1 + n;                      // n
  int* rs1 = cnt2 + n;                       // n+1
  int* rs2 = rs1 + (n + 1);                  // n+1
  int* cur1 = rs2 + (n + 1);                 // n
  int* cur2 = cur1 + n;                      // n
  int* aux1 = cur2 + n;                      // 512
  int* aux2 = aux1 + 512;                    // 512
  int2* ep1 = (int2*)(aux2 + 512);           // E1 (8B each)
  int2* ep2 = ep1 + E1;                      // E2

  auto blocks = [](long long t, int bs) { return (int)((t + bs - 1) / bs); };
  const int NB = blocks(n, 512);  // 98 <= 512

  // embed (independent of CSR build)
  embed_gemm_relu<<<blocks(n / 4, 4), 256, 0, stream>>>(x, w_embed, r0, n / 4);

  // CSR build for both graphs
  hipMemsetAsync(cnt1, 0, (size_t)2 * n * sizeof(int), stream);
  histo<<<blocks(E1, 256), 256, 0, stream>>>(a1_idx, E1, cnt1);
  histo<<<blocks(E2, 256), 256, 0, stream>>>(a2_idx, E2, cnt2);
  scan_blocks<<<NB, 512, 0, stream>>>(cnt1, n, rs1, aux1);
  scan_blocks<<<NB, 512, 0, stream>>>(cnt2, n, rs2, aux2);
  scan_aux<<<1, 512, 0, stream>>>(aux1, NB);
  scan_aux<<<1, 512, 0, stream>>>(aux2, NB);
  add_offsets<<<NB, 512, 0, stream>>>(rs1, cur1, aux1, n, E1);
  add_offsets<<<NB, 512, 0, stream>>>(rs2, cur2, aux2, n, E2);
  scatter_edges<<<blocks(E1, 256), 256, 0, stream>>>(a1_idx, a1_val, E1, cur1, ep1);
  scatter_edges<<<blocks(E2, 256), 256, 0, stream>>>(a2_idx, a2_val, E2, cur2, ep2);

  // hop 1: width 64 -> r1 [N,128]  (ReLU fused)
  spmm_csr<1><<<blocks(n, 4), 256, 0, stream>>>(rs1, ep1, r0, r1, 128, n);
  spmm_csr<1><<<blocks(n, 4), 256, 0, stream>>>(rs2, ep2, r0, r1 + 64, 128, n);

  // hop 2: width 128 -> r2 [N,256]  (ReLU fused)
  spmm_csr<2><<<blocks(n, 4), 256, 0, stream>>>(rs1, ep1, r1, r2, 256, n);
  spmm_csr<2><<<blocks(n, 4), 256, 0, stream>>>(rs2, ep2, r1, r2 + 128, 256, n);

  classify_softmax<<<blocks(n, 4), 256, 0, stream>>>(r0, r1, r2, w_classify, out, n);
}

// Round 4
// 595.810 us; speedup vs baseline: 10.4123x; 1.1230x over previous
//
#include <hip/hip_runtime.h>
#include <hip/hip_bf16.h>

// H2GCN inference:
//   r0 = relu(x @ w_embed)                       [N,64]
//   r1 = relu([spmm(a1,r0) | spmm(a2,r0)])       [N,128]
//   r2 = relu([spmm(a1,r1) | spmm(a2,r1)])       [N,256]
//   out = softmax([r0|r1|r2] @ w_classify)       [N,16]
// SpMM: on-device CSR build. The edge scatter is range-partitioned by
// output row across XCDs (blockIdx%8 -> XCD round-robin): each group scans
// all edges coalesced but writes only its row range, so every epack cache
// line is written by ONE XCD -> 1x writeback instead of 8x partial
// writebacks from non-coherent per-XCD L2s (round-3 counter evidence:
// WRITE_SIZE was exactly 8x the logical bytes).

#define F_IN 256
#define H_DIM 64

// ---------------- embed GEMM: r0 = relu(x @ w) ----------------
__global__ __launch_bounds__(256) void embed_gemm_relu(
    const float* __restrict__ x, const float* __restrict__ w,
    float* __restrict__ r0, int n_tiles) {
  __shared__ float ws[F_IN * H_DIM];  // 64 KB
  for (int i = threadIdx.x; i < F_IN * H_DIM / 4; i += 256)
    ((float4*)ws)[i] = ((const float4*)w)[i];
  __syncthreads();
  int lane = threadIdx.x & 63;
  int tile = blockIdx.x * 4 + (threadIdx.x >> 6);
  if (tile >= n_tiles) return;
  int row = tile * 4;
  float xv[4][4];
#pragma unroll
  for (int j = 0; j < 4; ++j)
#pragma unroll
    for (int q = 0; q < 4; ++q)
      xv[j][q] = x[(size_t)(row + j) * F_IN + q * 64 + lane];
  float acc[4] = {0.f, 0.f, 0.f, 0.f};
#pragma unroll
  for (int k = 0; k < 256; ++k) {
    float wk = ws[k * 64 + lane];
#pragma unroll
    for (int j = 0; j < 4; ++j) {
      float xb = __uint_as_float(
          __builtin_amdgcn_readlane(__float_as_uint(xv[j][k >> 6]), k & 63));
      acc[j] = fmaf(xb, wk, acc[j]);
    }
  }
#pragma unroll
  for (int j = 0; j < 4; ++j)
    r0[(size_t)(row + j) * H_DIM + lane] = fmaxf(acc[j], 0.f);
}

// ---------------- CSR build (both graphs fused per stage) ---------------
__global__ __launch_bounds__(256) void histo2(
    const int* __restrict__ i1, int E1, int* __restrict__ c1,
    const int* __restrict__ i2, int E2, int* __restrict__ c2, int HB1) {
  int b = blockIdx.x;
  if (b < HB1) {
    int i = b * 256 + threadIdx.x;
    if (i < E1) atomicAdd(&c1[i1[i]], 1);
  } else {
    int i = (b - HB1) * 256 + threadIdx.x;
    if (i < E2) atomicAdd(&c2[i2[i]], 1);
  }
}

// exclusive scan, level 1: per-block (512 elements); both graphs in one grid
__global__ __launch_bounds__(512) void scan_blocks2(
    const int* __restrict__ c1, int* __restrict__ e1, int* __restrict__ a1,
    const int* __restrict__ c2, int* __restrict__ e2, int* __restrict__ a2,
    int n, int NB) {
  const int* cnt;
  int* exc;
  int* aux;
  int blk = blockIdx.x;
  if (blk < NB) {
    cnt = c1; exc = e1; aux = a1;
  } else {
    cnt = c2; exc = e2; aux = a2; blk -= NB;
  }
  __shared__ int tmp[512];
  int i = blk * 512 + threadIdx.x;
  int v = (i < n) ? cnt[i] : 0;
  tmp[threadIdx.x] = v;
  __syncthreads();
#pragma unroll
  for (int d = 1; d < 512; d <<= 1) {
    int t = (threadIdx.x >= d) ? tmp[threadIdx.x - d] : 0;
    __syncthreads();
    tmp[threadIdx.x] += t;
    __syncthreads();
  }
  if (i < n) exc[i] = tmp[threadIdx.x] - v;
  if (threadIdx.x == 511) aux[blk] = tmp[511];
}

// exclusive scan, level 2: block 0 -> aux1, block 1 -> aux2 (nblk <= 512)
__global__ __launch_bounds__(512) void scan_aux2(int* __restrict__ a1,
                                                 int* __restrict__ a2,
                                                 int nblk) {
  int* aux = (blockIdx.x == 0) ? a1 : a2;
  __shared__ int tmp[512];
  int v = (threadIdx.x < nblk) ? aux[threadIdx.x] : 0;
  tmp[threadIdx.x] = v;
  __syncthreads();
#pragma unroll
  for (int d = 1; d < 512; d <<= 1) {
    int t = (threadIdx.x >= d) ? tmp[threadIdx.x - d] : 0;
    __syncthreads();
    tmp[threadIdx.x] += t;
    __syncthreads();
  }
  if (threadIdx.x < nblk) aux[threadIdx.x] = tmp[threadIdx.x] - v;
}

__global__ __launch_bounds__(512) void add_offsets2(
    int* __restrict__ rs1, int* __restrict__ cur1, const int* __restrict__ a1,
    int E1, int* __restrict__ rs2, int* __restrict__ cur2,
    const int* __restrict__ a2, int E2, int n, int NB) {
  int blk = blockIdx.x;
  int* rs;
  int* cur;
  const int* aux;
  int E;
  if (blk < NB) {
    rs = rs1; cur = cur1; aux = a1; E = E1;
  } else {
    rs = rs2; cur = cur2; aux = a2; E = E2; blk -= NB;
  }
  int i = blk * 512 + threadIdx.x;
  if (i < n) {
    int v = rs[i] + aux[blk];
    rs[i] = v;
    cur[i] = v;
  }
  if (blk == 0 && threadIdx.x == 0) rs[n] = E;
}

// XCD-range-partitioned scatter: group g = blockIdx&7 handles rows
// [g*chunk, (g+1)*chunk). All loads fully coalesced; non-matching lanes
// just skip the write. Graph1 gets SB1 blocks (multiple of 8), graph2 the
// rest (SB1%8==0 keeps blockIdx%8 == local%8).
__global__ __launch_bounds__(256) void scatter_ranged(
    const int* __restrict__ i1, const float* __restrict__ v1, int E1,
    int* __restrict__ cur1, int2* __restrict__ ep1,
    const int* __restrict__ i2, const float* __restrict__ v2, int E2,
    int* __restrict__ cur2, int2* __restrict__ ep2, int SB1, int SBtot,
    int n) {
  int b = blockIdx.x;
  const int* I;
  const float* V;
  int E, nb;
  int* cur;
  int2* ep;
  if (b < SB1) {
    I = i1; V = v1; E = E1; cur = cur1; ep = ep1; nb = SB1;
  } else {
    I = i2; V = v2; E = E2; cur = cur2; ep = ep2; nb = SBtot - SB1; b -= SB1;
  }
  int g = b & 7;
  int bg = b >> 3;
  int chunk = (n + 7) >> 3;
  int lo = g * chunk;
  int hi = min(n, lo + chunk);
  int stride = (nb >> 3) * 256;
  for (int i = bg * 256 + threadIdx.x; i < E; i += stride) {
    int r = I[i];
    int c = I[E + i];
    float v = V[i];
    if (r >= lo && r < hi) {
      int p = atomicAdd(&cur[r], 1);
      int2 pk;
      pk.x = c;
      pk.y = __float_as_int(v);
      ep[p] = pk;
    }
  }
}

// ---------------- gather-based CSR SpMM (+fused ReLU), both graphs ------
// One wave per output row. VEC=1 -> W=64 (4B/lane), VEC=2 -> W=128 (8B/lane).
// Blocks [0,SB) -> graph1 (col offset 0), [SB,2SB) -> graph2 (col offset W).
template <int VEC>
__global__ __launch_bounds__(256) void spmm_csr2(
    const int* __restrict__ rs1, const int2* __restrict__ ep1,
    const int* __restrict__ rs2, const int2* __restrict__ ep2,
    const float* __restrict__ in, float* __restrict__ out, int ld_out, int n,
    int SB) {
  constexpr int W = VEC * 64;
  const int* rs;
  const int2* epack;
  int coff;
  int blk = blockIdx.x;
  if (blk < SB) {
    rs = rs1; epack = ep1; coff = 0;
  } else {
    rs = rs2; epack = ep2; coff = W; blk -= SB;
  }
  int lane = threadIdx.x & 63;
  int row = blk * 4 + (threadIdx.x >> 6);
  if (row >= n) return;
  int s = rs[row], e = rs[row + 1];
  float acc0 = 0.f, acc1 = 0.f;
  int j = s;
  for (; j + 8 <= e; j += 8) {  // 8-deep MLP on gathers
    int2 ep[8];
#pragma unroll
    for (int u = 0; u < 8; ++u) ep[u] = epack[j + u];
    if (VEC == 1) {
      float xg[8];
#pragma unroll
      for (int u = 0; u < 8; ++u) xg[u] = in[(size_t)ep[u].x * W + lane];
#pragma unroll
      for (int u = 0; u < 8; ++u)
        acc0 = fmaf(__int_as_float(ep[u].y), xg[u], acc0);
    } else {
      float2 xg[8];
#pragma unroll
      for (int u = 0; u < 8; ++u)
        xg[u] = *(const float2*)&in[(size_t)ep[u].x * W + lane * 2];
#pragma unroll
      for (int u = 0; u < 8; ++u) {
        float v = __int_as_float(ep[u].y);
        acc0 = fmaf(v, xg[u].x, acc0);
        acc1 = fmaf(v, xg[u].y, acc1);
      }
    }
  }
  for (; j < e; ++j) {
    int2 ep = epack[j];
    float v = __int_as_float(ep.y);
    if (VEC == 1) {
      acc0 = fmaf(v, in[(size_t)ep.x * W + lane], acc0);
    } else {
      float2 xv = *(const float2*)&in[(size_t)ep.x * W + lane * 2];
      acc0 = fmaf(v, xv.x, acc0);
      acc1 = fmaf(v, xv.y, acc1);
    }
  }
  if (VEC == 1) {
    out[(size_t)row * ld_out + coff + lane] = fmaxf(acc0, 0.f);
  } else {
    float2 st;
    st.x = fmaxf(acc0, 0.f);
    st.y = fmaxf(acc1, 0.f);
    *(float2*)&out[(size_t)row * ld_out + coff + lane * 2] = st;
  }
}

// ---------------- classifier + softmax --------------------------------
__global__ __launch_bounds__(256) void classify_softmax(
    const float* __restrict__ r0, const float* __restrict__ r1,
    const float* __restrict__ r2, const float* __restrict__ wc,
    float* __restrict__ out, int n) {
  __shared__ float wls[448 * 16];  // 28 KB
  for (int i = threadIdx.x; i < 448 * 16 / 4; i += 256)
    ((float4*)wls)[i] = ((const float4*)wc)[i];
  __syncthreads();
  int lane = threadIdx.x & 63;
  int c = lane & 15;
  int part = lane >> 4;
  int node = blockIdx.x * 4 + (threadIdx.x >> 6);
  if (node >= n) return;

  float acc = 0.f;
  {  // r0: width 64, fbase 0
    const float* p = r0 + (size_t)node * 64 + part * 16;
#pragma unroll
    for (int j = 0; j < 4; ++j) {
      float4 rv = *(const float4*)(p + 4 * j);
      int fb = part * 16 + 4 * j;
      acc = fmaf(rv.x, wls[(fb + 0) * 16 + c], acc);
      acc = fmaf(rv.y, wls[(fb + 1) * 16 + c], acc);
      acc = fmaf(rv.z, wls[(fb + 2) * 16 + c], acc);
      acc = fmaf(rv.w, wls[(fb + 3) * 16 + c], acc);
    }
  }
  {  // r1: width 128, fbase 64
    const float* p = r1 + (size_t)node * 128 + part * 32;
#pragma unroll
    for (int j = 0; j < 8; ++j) {
      float4 rv = *(const float4*)(p + 4 * j);
      int fb = 64 + part * 32 + 4 * j;
      acc = fmaf(rv.x, wls[(fb + 0) * 16 + c], acc);
      acc = fmaf(rv.y, wls[(fb + 1) * 16 + c], acc);
      acc = fmaf(rv.z, wls[(fb + 2) * 16 + c], acc);
      acc = fmaf(rv.w, wls[(fb + 3) * 16 + c], acc);
    }
  }
  {  // r2: width 256, fbase 192
    const float* p = r2 + (size_t)node * 256 + part * 64;
#pragma unroll
    for (int j = 0; j < 16; ++j) {
      float4 rv = *(const float4*)(p + 4 * j);
      int fb = 192 + part * 64 + 4 * j;
      acc = fmaf(rv.x, wls[(fb + 0) * 16 + c], acc);
      acc = fmaf(rv.y, wls[(fb + 1) * 16 + c], acc);
      acc = fmaf(rv.z, wls[(fb + 2) * 16 + c], acc);
      acc = fmaf(rv.w, wls[(fb + 3) * 16 + c], acc);
    }
  }
  acc += __shfl_xor(acc, 16, 64);
  acc += __shfl_xor(acc, 32, 64);
  float m = acc;
#pragma unroll
  for (int d = 1; d < 16; d <<= 1) m = fmaxf(m, __shfl_xor(m, d, 64));
  float ex = __expf(acc - m);
  float s = ex;
#pragma unroll
  for (int d = 1; d < 16; d <<= 1) s += __shfl_xor(s, d, 64);
  if (lane < 16) out[(size_t)node * 16 + c] = ex / s;
}

extern "C" void kernel_launch(void* const* d_in, const int* in_sizes, int n_in,
                              void* d_out, int out_size, void* d_ws, size_t ws_size,
                              hipStream_t stream) {
  const float* x = (const float*)d_in[0];
  const int* a1_idx = (const int*)d_in[1];
  const float* a1_val = (const float*)d_in[2];
  const int* a2_idx = (const int*)d_in[3];
  const float* a2_val = (const float*)d_in[4];
  const float* w_embed = (const float*)d_in[5];
  const float* w_classify = (const float*)d_in[6];
  float* out = (float*)d_out;

  const int n = in_sizes[0] / F_IN;  // 50000
  const int E1 = in_sizes[2];        // 800000
  const int E2 = in_sizes[4];        // 1600000

  // workspace layout
  float* r0 = (float*)d_ws;                  // n*64
  float* r1 = r0 + (size_t)n * 64;           // n*128
  float* r2 = r1 + (size_t)n * 128;          // n*256
  int* cnt1 = (int*)(r2 + (size_t)n * 256);  // n
  int* cnt2 = cnt1 + n;                      // n
  int* rs1 = cnt2 + n;                       // n+1
  int* rs2 = rs1 + (n + 1);                  // n+1
  int* cur1 = rs2 + (n + 1);                 // n
  int* cur2 = cur1 + n;                      // n
  int* aux1 = cur2 + n;                      // 512
  int* aux2 = aux1 + 512;                    // 512
  int2* ep1 = (int2*)(aux2 + 512);           // E1 (8B each)
  int2* ep2 = ep1 + E1;                      // E2

  auto blocks = [](long long t, int bs) { return (int)((t + bs - 1) / bs); };
  const int NB = blocks(n, 512);        // 98
  const int HB1 = blocks(E1, 256);      // 3125
  const int HB2 = blocks(E2, 256);      // 6250
  const int SC1 = 1024, SC2 = 2048;     // scatter blocks (mult of 8)
  const int SB = blocks(n, 4);          // spmm blocks per graph

  // embed (independent of CSR build)
  embed_gemm_relu<<<blocks(n / 4, 4), 256, 0, stream>>>(x, w_embed, r0, n / 4);

  // CSR build for both graphs (fused per stage)
  hipMemsetAsync(cnt1, 0, (size_t)2 * n * sizeof(int), stream);
  histo2<<<HB1 + HB2, 256, 0, stream>>>(a1_idx, E1, cnt1, a2_idx, E2, cnt2, HB1);
  scan_blocks2<<<2 * NB, 512, 0, stream>>>(cnt1, rs1, aux1, cnt2, rs2, aux2, n, NB);
  scan_aux2<<<2, 512, 0, stream>>>(aux1, aux2, NB);
  add_offsets2<<<2 * NB, 512, 0, stream>>>(rs1, cur1, aux1, E1, rs2, cur2, aux2,
                                           E2, n, NB);
  scatter_ranged<<<SC1 + SC2, 256, 0, stream>>>(a1_idx, a1_val, E1, cur1, ep1,
                                                a2_idx, a2_val, E2, cur2, ep2,
                                                SC1, SC1 + SC2, n);

  // hop 1: width 64 -> r1 [N,128]  (ReLU fused)
  spmm_csr2<1><<<2 * SB, 256, 0, stream>>>(rs1, ep1, rs2, ep2, r0, r1, 128, n, SB);
  // hop 2: width 128 -> r2 [N,256]  (ReLU fused)
  spmm_csr2<2><<<2 * SB, 256, 0, stream>>>(rs1, ep1, rs2, ep2, r1, r2, 256, n, SB);

  classify_softmax<<<blocks(n, 4), 256, 0, stream>>>(r0, r1, r2, w_classify, out, n);
}